// Round 6
// baseline (384.341 us; speedup 1.0000x reference)
//
#include <hip/hip_runtime.h>
#include <math.h>

#define HH 192
#define WW 192
#define CC 64
#define CHW (HH*WW)
#define SS 16
#define NB 12
#define NBLK 144
#define NSH 49
#define UROW 22          // union region rows
#define RW 24            // region row elems staged (16B-aligned from cbase4)
#define RDW 13           // dwords per packed bf16 copy-row (12 data + 1 pad)
#define NCHK 2           // channels per MFMA K-step
#define NT 10            // N-tiles of 16 covering 154 (yw,u) columns
#define LN 160           // S row stride
#define CSTRIDE (UROW*2*RDW)   // 572 dw per channel in region slice
#define REGDW (NCHK*CSTRIDE)   // 1144 dw region per wave
// overlay offsets (dwords; valid after region is dead)
#define S0   0
#define RS0  (16*LN)           // 2560
#define CS0  (RS0 + UROW*RW)   // 3088
#define ASUM0 (CS0 + 154)      // 3242
#define OVL_N (ASUM0 + 1)
#define LDS_DW (4*REGDW)       // 4576 dwords = 18304 B

typedef __attribute__((ext_vector_type(4))) float f32x4;
typedef __attribute__((ext_vector_type(8))) short bf16x8;

__device__ __forceinline__ int iclamp(int v, int lo, int hi){ return v<lo?lo:(v>hi?hi:v); }

__device__ __forceinline__ unsigned f2bf(float f){
  unsigned u = __float_as_uint(f);
  return (u + 0x7FFFu + ((u >> 16) & 1u)) >> 16;
}
__device__ __forceinline__ unsigned pk2(float lo, float hi){
  return f2bf(lo) | (f2bf(hi) << 16);
}

// NZ: channel split across grid.z (z-partial distances written for NZ=2)
template<int NZ>
__global__ __launch_bounds__(256, 8) void dist_kernel(
    const float* __restrict__ fm1, const float* __restrict__ fm2,
    float* __restrict__ partial)
{
  __shared__ unsigned smu[LDS_DW];
  float* smf = (float*)smu;

  const int blk = blockIdx.x;           // 0..143
  const int b   = blockIdx.y;           // 0..7
  const int z   = blockIdx.z;           // 0..NZ-1
  const int by  = blk / NB, bx = blk - by*NB;
  const int ys  = by*SS, xs = bx*SS;
  const int rbase = iclamp(ys-3, 0, HH-UROW);
  const int ey = (ys-3) - rbase;
  const int cbase  = iclamp(xs-3, 0, WW-UROW);
  const int cbase4 = (bx == 0) ? 0 : ((bx == NB-1) ? (WW-RW) : (xs-4));
  const int OX = cbase - cbase4;        // 0/1/2
  const int ex = (xs-3) - cbase;        // -3/0/3

  const int tid  = threadIdx.x;
  const int wid  = tid >> 6;
  const int lane = tid & 63;
  const int row16 = lane & 15;          // A: y row / B: n within tile
  const int kb    = lane >> 4;          // 0..3 k-block
  const int coff  = lane >> 5;          // channel within K-step (0..1)
  const int x0    = ((lane >> 4) & 1) * 8;

  const int NCHUNK = (CC/NZ)/4/NCHK;    // 4 (NZ=2) or 8 (NZ=1)
  const int c0w = z*(CC/NZ) + wid*(NCHK*NCHUNK);
  const int regbase = wid * REGDW;

  const float* f1b = fm1 + (size_t)b*CC*CHW;
  const float* f2b = fm2 + (size_t)b*CC*CHW;

  // ---- per-lane B-fragment LDS dword bases per N-tile (chunk-invariant)
  int boff[NT];
#pragma unroll
  for (int nt = 0; nt < NT; ++nt) {
    int n  = nt*16 + row16;
    int n7 = n / 7;
    int o  = n - n7*7;
    int yw = n7 > (UROW-1) ? (UROW-1) : n7;
    int e  = OX + o + x0;
    int p  = e & 1;
    int d0 = (e - p) >> 1;
    boff[nt] = regbase + ((coff*UROW + yw)*2 + p)*RDW + d0;
  }

  // ---- staging position assignment (static; 264 float2-pairs per channel)
  int pyw[5], pdp[5];
#pragma unroll
  for (int i = 0; i < 5; ++i) {
    int pi = lane + 64*i;
    int piq = (pi < 264) ? pi : 0;
    pyw[i] = piq / 12;
    pdp[i] = piq - 12*pyw[i];
  }
  const int aoff = (ys + row16)*WW + xs + x0;

  f32x4 acc[NT];
#pragma unroll
  for (int nt = 0; nt < NT; ++nt) acc[nt] = (f32x4){0.f,0.f,0.f,0.f};
  float rsa[5] = {0.f,0.f,0.f,0.f,0.f};
  float rsb[5] = {0.f,0.f,0.f,0.f,0.f};
  float asum = 0.f;

  // ================= main chunk loop (wave-private region, no barriers) ====
  for (int ck = 0; ck < NCHUNK; ++ck) {
    // ---- A fragment loads first (independent; overlaps staging latency)
    const float* ap = f1b + (size_t)(c0w + ck*NCHK + coff)*CHW + aoff;
    float4 a0 = *(const float4*)ap;
    float4 a1 = *(const float4*)(ap + 4);

    // ---- stage 2 channels of 22x24 region as 2 parity-packed bf16 copies
    const float* f2c = f2b + (size_t)(c0w + ck*NCHK)*CHW;
#pragma unroll
    for (int i = 0; i < 5; ++i) {
      if (i < 4 || lane < 8) {
        const int go = (rbase + pyw[i])*WW + cbase4 + 2*pdp[i];
        const int wo = regbase + (pyw[i]*2)*RDW + pdp[i];
        const bool has2 = (pdp[i] < 11);
#pragma unroll
        for (int ch = 0; ch < NCHK; ++ch) {
          const float* g = f2c + (size_t)ch*CHW + go;
          float2 v01 = *(const float2*)g;
          float e2 = has2 ? g[2] : 0.f;
          smu[wo + ch*CSTRIDE]       = pk2(v01.x, v01.y);  // elems (2d,2d+1)
          smu[wo + ch*CSTRIDE + RDW] = pk2(v01.y, e2);     // elems (2d+1,2d+2)
          rsa[i] = fmaf(v01.x, v01.x, rsa[i]);
          rsb[i] = fmaf(v01.y, v01.y, rsb[i]);
        }
      }
    }

    // ---- finish A fragment (pack + a^2)
    asum = fmaf(a0.x,a0.x, fmaf(a0.y,a0.y, fmaf(a0.z,a0.z, fmaf(a0.w,a0.w, asum))));
    asum = fmaf(a1.x,a1.x, fmaf(a1.y,a1.y, fmaf(a1.z,a1.z, fmaf(a1.w,a1.w, asum))));
    union { unsigned u[4]; bf16x8 v; } A_;
    A_.u[0] = pk2(a0.x, a0.y); A_.u[1] = pk2(a0.z, a0.w);
    A_.u[2] = pk2(a1.x, a1.y); A_.u[3] = pk2(a1.z, a1.w);

    // ---- 10 N-tiles, one K-step each (compiler inserts lgkmcnt for LDS dep)
#pragma unroll
    for (int nt = 0; nt < NT; ++nt) {
      const unsigned* bp = smu + boff[nt];
      union { unsigned u[4]; bf16x8 v; } B_;
      B_.u[0] = bp[0]; B_.u[1] = bp[1]; B_.u[2] = bp[2]; B_.u[3] = bp[3];
      acc[nt] = __builtin_amdgcn_mfma_f32_16x16x32_bf16(A_.v, B_.v, acc[nt], 0, 0, 0);
    }
  }

  // ================= merge phase ==========================================
  __syncthreads();                       // region dead; overlay S/RS/CS
  for (int i = tid; i < OVL_N; i += 256) smf[i] = 0.f;
  __syncthreads();

  // S[y][n] merge: C layout col=lane&15 (n), row=(lane>>4)*4+reg (y)
#pragma unroll
  for (int nt = 0; nt < NT; ++nt) {
#pragma unroll
    for (int r = 0; r < 4; ++r) {
      atomicAdd(&smf[S0 + (kb*4 + r)*LN + nt*16 + row16], acc[nt][r]);
    }
  }
  // RS merge (sum over this WG's channels of w^2 per region position)
#pragma unroll
  for (int i = 0; i < 5; ++i) {
    if (i < 4 || lane < 8) {
      atomicAdd(&smf[RS0 + pyw[i]*RW + 2*pdp[i]    ], rsa[i]);
      atomicAdd(&smf[RS0 + pyw[i]*RW + 2*pdp[i] + 1], rsb[i]);
    }
  }
  {
    float v = asum;
#pragma unroll
    for (int off = 32; off; off >>= 1) v += __shfl_xor(v, off);
    if (lane == 0) atomicAdd(&smf[ASUM0], v);
  }
  __syncthreads();

  // ---- CS[yw][o]: sliding 16-window sums of RS along x
  if (tid < 154) {
    int yw = tid / 7, o = tid - 7*yw;
    float s = 0.f;
#pragma unroll
    for (int x = 0; x < 16; ++x) s += smf[RS0 + yw*RW + OX + o + x];
    smf[CS0 + tid] = s;
  }
  __syncthreads();

  // ---- z-partial distances (49 values)
  if constexpr (NZ == 2) {
    if (tid < NSH) {
      int t = tid / 7, u = tid - 7*t;
      int oyt = iclamp(t + ey, 0, 6);
      int o   = iclamp(u + ex, 0, 6);
      float s = smf[ASUM0];
#pragma unroll
      for (int y = 0; y < 16; ++y) {
        int n = (y + oyt)*7 + o;
        s += smf[CS0 + n] - 2.f*smf[S0 + y*LN + n];
      }
      partial[((size_t)(b*NBLK + blk)*2 + z)*NSH + tid] = s;   // raw z-partial
    }
  } else {
    if (tid < 64) {
      int tu = tid < NSH ? tid : NSH-1;
      int t = tu / 7, u = tu - 7*t;
      int oyt = iclamp(t + ey, 0, 6);
      int o   = iclamp(u + ex, 0, 6);
      float s = smf[ASUM0];
#pragma unroll
      for (int y = 0; y < 16; ++y) {
        int n = (y + oyt)*7 + o;
        s += smf[CS0 + n] - 2.f*smf[S0 + y*LN + n];
      }
#pragma unroll
      for (int off = 32; off; off >>= 1) s = fminf(s, __shfl_xor(s, off));
      if (tid == 0) partial[(size_t)b*NBLK + blk] = s;         // raw min
    }
  }
}

template<int NZ>
__global__ void topk_kernel(const float* __restrict__ partial, float* __restrict__ out)
{
  const int b = blockIdx.x;            // 0..7
  const int lane = threadIdx.x;        // 0..63
  const float INF = __builtin_inff();

  float v0 = INF, v1 = INF, v2 = INF;
  if constexpr (NZ == 2) {
#pragma unroll
    for (int i = 0; i < 3; i++) {
      int blk = lane + 64*i;
      if (blk < NBLK) {
        const float* p = partial + (size_t)(b*NBLK + blk)*2*NSH;
        float m = INF;
        for (int k = 0; k < NSH; k++) m = fminf(m, p[k] + p[k+NSH]);
        if (i == 0) v0 = m; else if (i == 1) v1 = m; else v2 = m;
      }
    }
  } else {
    const float* p = partial + (size_t)b*NBLK;
    v0 = p[lane];
    v1 = p[lane + 64];
    v2 = (lane < 16) ? p[lane + 128] : INF;
  }

  float sum = 0.f;
  for (int it = 0; it < 16; ++it) {
    float lm = fminf(v0, fminf(v1, v2));
    float m = lm;
#pragma unroll
    for (int off = 32; off; off >>= 1) m = fminf(m, __shfl_xor(m, off));
    sum += m;
    unsigned long long mask = __ballot(lm == m);
    int leader = __ffsll(mask) - 1;
    if (lane == leader) {
      if (v0 == m)      v0 = INF;
      else if (v1 == m) v1 = INF;
      else              v2 = INF;
    }
  }
  if (lane == 0) out[b] = sum * (1.0f/((float)CC*SS*SS));
}

extern "C" void kernel_launch(void* const* d_in, const int* in_sizes, int n_in,
                              void* d_out, int out_size, void* d_ws, size_t ws_size,
                              hipStream_t stream)
{
  const float* fm1 = (const float*)d_in[0];
  const float* fm2 = (const float*)d_in[1];
  float* out  = (float*)d_out;
  float* scratch = (float*)d_ws;

  const size_t NEED = (size_t)8 * NBLK * 2 * NSH * sizeof(float);  // 451,584 B
  if (ws_size >= NEED) {
    dist_kernel<2><<<dim3(NBLK, 8, 2), 256, 0, stream>>>(fm1, fm2, scratch);
    topk_kernel<2><<<8, 64, 0, stream>>>(scratch, out);
  } else {
    dist_kernel<1><<<dim3(NBLK, 8, 1), 256, 0, stream>>>(fm1, fm2, scratch);
    topk_kernel<1><<<8, 64, 0, stream>>>(scratch, out);
  }
}

// Round 7
// 128.918 us; speedup vs baseline: 2.9813x; 2.9813x over previous
//
#include <hip/hip_runtime.h>
#include <math.h>

#define HH 192
#define WW 192
#define CC 64
#define CHW (HH*WW)
#define SS 16
#define NB 12
#define NBLK 144
#define CCH 8            // channels per LDS chunk
#define UROW 22          // union region rows
#define LROW 28          // padded LDS row stride (floats)
#define QN 6             // float4 staged per row (24 floats)
#define NSH 49
#define STAGE_N (CCH*UROW*QN)    // 1056 float4 per chunk
#define PAD_IDX (CCH*UROW*LROW)  // 4928: pad float4 slot for inactive staging lanes
#define LDS_FLOATS (PAD_IDX + 4)

__device__ __forceinline__ int iclamp(int v, int lo, int hi){ return v<lo?lo:(v>hi?hi:v); }

// EX: column-shift class (-3 left, 0 interior, +3 right); OX: compile-time col offset
template<int EX, int OX>
__device__ __forceinline__ void run_chunks(
    const float* __restrict__ f1b, const float* __restrict__ f2b,
    float* sm, int tid, int t, int y, int h8, bool active,
    int ys, int xs, int rbase, int ey, float acc[7])
{
  const int cbase4 = (EX == -3) ? 0 : ((EX == 0) ? (xs - 4) : (WW - LROW + 4)); // 0/xs-4/168

  // ---- static staging slot decomposition (5 slots/thread, pad for tail)
  int goff[5], lidx[5];
#pragma unroll
  for (int j = 0; j < 5; ++j) {
    int i  = tid + 256*j;
    bool v = (i < STAGE_N);
    int iq = v ? i : 0;
    int ch  = iq / (UROW*QN);
    int rem = iq - ch*(UROW*QN);
    int r   = rem / QN;
    int q   = rem - r*QN;
    goff[j] = ch*CHW + (rbase + r)*WW + cbase4 + 4*q;   // valid address even for pad
    lidx[j] = v ? (ch*(UROW*LROW) + r*LROW + 4*q) : PAD_IDX;
  }

  const int oyt = iclamp(t + ey, 0, 6);                 // this thread's dh row offset
  const float* ap0 = f1b + (size_t)(ys + y)*WW + xs + h8;
  const int wrow = (y + oyt)*LROW + h8;

  // ---- prologue: prefetch chunk 0 into registers
  float4 pf[5];
#pragma unroll
  for (int j = 0; j < 5; ++j) pf[j] = *(const float4*)(f2b + goff[j]);

  for (int ck = 0; ck < CC/CCH; ++ck) {
    __syncthreads();                    // consumers of previous chunk done
#pragma unroll
    for (int j = 0; j < 5; ++j) *(float4*)&sm[lidx[j]] = pf[j];
    if (ck + 1 < CC/CCH) {
      const float* f2n = f2b + (size_t)(ck+1)*CCH*CHW;  // next chunk in flight
#pragma unroll
      for (int j = 0; j < 5; ++j) pf[j] = *(const float4*)(f2n + goff[j]);
    }
    __syncthreads();                    // LDS ready

    if (active) {
      const float* apc = ap0 + (size_t)ck*CCH*CHW;
#pragma unroll 2
      for (int c = 0; c < CCH; ++c) {
        const float* ap = apc + (size_t)c*CHW;          // fm1 half-row (L1-reused x7)
        float4 v0 = *(const float4*)(ap + 0);
        float4 v1 = *(const float4*)(ap + 4);
        float a[8] = {v0.x,v0.y,v0.z,v0.w, v1.x,v1.y,v1.z,v1.w};
        const float* wp = sm + c*(UROW*LROW) + wrow;
        float w[16];
#pragma unroll
        for (int jq = 0; jq < 4; ++jq) {
          float4 vv = *(const float4*)(wp + 4*jq);      // aligned ds_read_b128
          w[4*jq]=vv.x; w[4*jq+1]=vv.y; w[4*jq+2]=vv.z; w[4*jq+3]=vv.w;
        }
#pragma unroll
        for (int u = 0; u < 7; ++u) {
          const int o = ((u+EX) < 0 ? 0 : ((u+EX) > 6 ? 6 : (u+EX))) + OX;  // compile-time
          float s0 = 0.f, s1 = 0.f;
#pragma unroll
          for (int x = 0; x < 8; x += 2) {
            float d0 = a[x]   - w[o+x];
            float d1 = a[x+1] - w[o+x+1];
            s0 = fmaf(d0, d0, s0);
            s1 = fmaf(d1, d1, s1);
          }
          acc[u] += s0 + s1;
        }
      }
    }
  }
}

__global__ __launch_bounds__(256, 4) void dist_kernel(
    const float* __restrict__ fm1, const float* __restrict__ fm2,
    float* __restrict__ partial)
{
  __shared__ float sm[LDS_FLOATS];     // 19,728 B; reduction overlaid after compute

  // XCD-chunked swizzle: each XCD owns one batch, blocks in raster order (L2 halo reuse)
  const int wg  = blockIdx.x;          // 0..1151
  const int b   = wg & 7;
  const int blk = wg >> 3;             // 0..143
  const int by  = blk / NB, bx = blk - by*NB;
  const int ys  = by*SS, xs = bx*SS;
  const int rbase = iclamp(ys-3, 0, HH-UROW);
  const int ey = (ys-3) - rbase;       // in {-3,0,3}

  const int tid = threadIdx.x;
  const int t   = tid >> 5;            // 0..7 ; t<7 active (dh = t-3)
  const int y   = (tid & 31) >> 1;     // 0..15 row within block
  const int h8  = (tid & 1) * 8;       // x-half: cols [h8, h8+8)
  const bool active = (t < 7);

  const float* f1b = fm1 + (size_t)b*CC*CHW;
  const float* f2b = fm2 + (size_t)b*CC*CHW;

  float acc[7];
#pragma unroll
  for (int k = 0; k < 7; k++) acc[k] = 0.f;

  if (bx == 0)
    run_chunks<-3,0>(f1b, f2b, sm, tid, t, y, h8, active, ys, xs, rbase, ey, acc);
  else if (bx == NB-1)
    run_chunks< 3,2>(f1b, f2b, sm, tid, t, y, h8, active, ys, xs, rbase, ey, acc);
  else
    run_chunks< 0,1>(f1b, f2b, sm, tid, t, y, h8, active, ys, xs, rbase, ey, acc);

  __syncthreads();                     // region dead; overlay reduction buffer
  float* distk = sm;
#pragma unroll
  for (int u = 0; u < 7; ++u) {
    float v = acc[u];
#pragma unroll
    for (int off = 16; off; off >>= 1) v += __shfl_xor(v, off);
    if (active && (tid & 31) == 0) distk[t*7 + u] = v;
  }
  __syncthreads();

  if (tid < 64) {
    float v = (tid < NSH) ? distk[tid] : __builtin_inff();
#pragma unroll
    for (int off = 32; off; off >>= 1) v = fminf(v, __shfl_xor(v, off));
    if (tid == 0) partial[(size_t)b*NBLK + blk] = v;   // raw min
  }
}

__global__ void topk_kernel(const float* __restrict__ partial, float* __restrict__ out)
{
  const int b = blockIdx.x;            // 0..7
  const int lane = threadIdx.x;        // 0..63
  const float INF = __builtin_inff();

  const float* p = partial + (size_t)b*NBLK;
  float v0 = p[lane];
  float v1 = p[lane + 64];
  float v2 = (lane < 16) ? p[lane + 128] : INF;

  float sum = 0.f;
  for (int it = 0; it < 16; ++it) {
    float lm = fminf(v0, fminf(v1, v2));
    float m = lm;
#pragma unroll
    for (int off = 32; off; off >>= 1) m = fminf(m, __shfl_xor(m, off));
    sum += m;
    unsigned long long mask = __ballot(lm == m);
    int leader = __ffsll(mask) - 1;
    if (lane == leader) {
      if (v0 == m)      v0 = INF;
      else if (v1 == m) v1 = INF;
      else              v2 = INF;
    }
  }
  if (lane == 0) out[b] = sum * (1.0f/((float)CC*SS*SS));
}

extern "C" void kernel_launch(void* const* d_in, const int* in_sizes, int n_in,
                              void* d_out, int out_size, void* d_ws, size_t ws_size,
                              hipStream_t stream)
{
  const float* fm1 = (const float*)d_in[0];
  const float* fm2 = (const float*)d_in[1];
  float* out  = (float*)d_out;
  float* scratch = (float*)d_ws;       // 8*144 floats

  dist_kernel<<<8*NBLK, 256, 0, stream>>>(fm1, fm2, scratch);
  topk_kernel<<<8, 64, 0, stream>>>(scratch, out);
}

// Round 8
// 95.661 us; speedup vs baseline: 4.0177x; 1.3477x over previous
//
#include <hip/hip_runtime.h>
#include <math.h>

#define HH 192
#define WW 192
#define CC 64
#define CHW (HH*WW)
#define SS 16
#define NB 12
#define NBLK 144
#define CCH 8            // channels per LDS chunk
#define UROW 22          // union region rows
#define LROW 28          // padded LDS row stride (floats)
#define QN 6             // float4 staged per row (24 floats)
#define NSH 49
#define STAGE_N (CCH*UROW*QN)   // 1056 float4 per chunk

__device__ __forceinline__ int iclamp(int v, int lo, int hi){ return v<lo?lo:(v>hi?hi:v); }

// EX: column-shift class (-3 left, 0 interior, +3 right); OX: compile-time col offset
template<int EX, int OX, int NCH>
__device__ __forceinline__ void run_chunks(
    const float* __restrict__ f1b, const float* __restrict__ f2b,
    float* sm, int tid, int t, int y, int h8, bool active,
    int ys, int xs, int rbase, int ey, int cc0, float acc[7])
{
  const int cbase4 = (EX == -3) ? 0 : ((EX == 0) ? (xs - 4) : (WW - LROW + 4));
  const int oyt = iclamp(t + ey, 0, 6);                 // row offset for this thread's dh
  const float* ap0 = f1b + (size_t)(ys + y)*WW + xs + h8;
  const int wrow = (y + oyt)*LROW + h8;                 // fixed per thread

  for (int ch0 = 0; ch0 < NCH; ch0 += CCH) {
    const int cc = cc0 + ch0;
    // ---- stage fm2 union region [cc..cc+7][rbase..+21][cbase4..+23], float4 both sides
    for (int i = tid; i < STAGE_N; i += 256) {
      int ch  = i / (UROW*QN);
      int rem = i - ch*(UROW*QN);
      int r   = rem / QN;
      int q   = rem - r*QN;
      *(float4*)&sm[ch*(UROW*LROW) + r*LROW + 4*q] =
        *(const float4*)(f2b + (size_t)(cc+ch)*CHW + (size_t)(rbase+r)*WW + cbase4 + 4*q);
    }
    __syncthreads();

    if (active) {
#pragma unroll 2
      for (int c = 0; c < CCH; c++) {
        // fm1 half-row from global (L1/L2-resident; 7x reuse across t)
        const float* ap = ap0 + (size_t)(cc + c)*CHW;
        float a[8];
        {
          float4 v0 = *(const float4*)(ap + 0);
          float4 v1 = *(const float4*)(ap + 4);
          a[0]=v0.x; a[1]=v0.y; a[2]=v0.z; a[3]=v0.w;
          a[4]=v1.x; a[5]=v1.y; a[6]=v1.z; a[7]=v1.w;
        }
        // fm2 row for this thread's dh: 16 floats starting at col h8
        const float* wp = sm + c*(UROW*LROW) + wrow;
        float w[16];
#pragma unroll
        for (int j = 0; j < 4; j++) {
          float4 v = *(const float4*)(wp + 4*j);        // aligned ds_read_b128
          w[4*j]=v.x; w[4*j+1]=v.y; w[4*j+2]=v.z; w[4*j+3]=v.w;
        }
#pragma unroll
        for (int u = 0; u < 7; u++) {
          const int o = ((u+EX) < 0 ? 0 : ((u+EX) > 6 ? 6 : (u+EX))) + OX;  // compile-time
          float s0 = 0.f, s1 = 0.f;
#pragma unroll
          for (int x = 0; x < 8; x += 2) {
            float d0 = a[x]   - w[o+x];
            float d1 = a[x+1] - w[o+x+1];
            s0 = fmaf(d0, d0, s0);
            s1 = fmaf(d1, d1, s1);
          }
          acc[u] += s0 + s1;
        }
      }
    }
    __syncthreads();
  }
}

// NZ: channel split. 1D grid with XCD-pinned swizzle (batch = wg&7 stays fixed per XCD).
template<int NZ>
__global__ __launch_bounds__(256, 8) void dist_kernel(
    const float* __restrict__ fm1, const float* __restrict__ fm2,
    float* __restrict__ partial)
{
  __shared__ float sm[CCH*UROW*LROW];   // 19,712 B; distk overlaid after compute

  // swizzle: wg in [0, NZ*1152). Pass p = wg/1152 (z), within-pass: b=wg&7, blk=raster.
  const int wg  = blockIdx.x;
  const int z   = wg >= 8*NBLK ? 1 : 0;           // 0..NZ-1 (NZ<=2)
  const int w2  = wg - z*8*NBLK;
  const int b   = w2 & 7;                          // batch pinned per XCD
  const int blk = w2 >> 3;                         // 0..143 raster (halo L2 reuse)
  const int by  = blk / NB, bx = blk - by*NB;
  const int ys  = by*SS, xs = bx*SS;
  const int rbase = iclamp(ys-3, 0, HH-UROW);
  const int ey = (ys-3) - rbase;       // in {-3,0,3}

  const int tid = threadIdx.x;
  const int t   = tid >> 5;            // 0..7 ; t<7 active (dh = t-3)
  const int y   = (tid & 31) >> 1;     // 0..15 row within block
  const int h8  = (tid & 1) * 8;       // x-half: cols [h8, h8+8)
  const bool active = (t < 7);

  const float* f1b = fm1 + (size_t)b*CC*CHW;
  const float* f2b = fm2 + (size_t)b*CC*CHW;

  const int cc0 = z * (CC/NZ);

  float acc[7];
#pragma unroll
  for (int k = 0; k < 7; k++) acc[k] = 0.f;

  if (bx == 0)
    run_chunks<-3,0,CC/NZ>(f1b, f2b, sm, tid, t, y, h8, active, ys, xs, rbase, ey, cc0, acc);
  else if (bx == NB-1)
    run_chunks< 3,2,CC/NZ>(f1b, f2b, sm, tid, t, y, h8, active, ys, xs, rbase, ey, cc0, acc);
  else
    run_chunks< 0,1,CC/NZ>(f1b, f2b, sm, tid, t, y, h8, active, ys, xs, rbase, ey, cc0, acc);

  // ---- reduce acc[u] over each 32-lane t-group; leaders write distk[t*7+u]
  float* distk = sm;                   // overlay (past final barrier of run_chunks)
#pragma unroll
  for (int u = 0; u < 7; u++) {
    float v = acc[u];
#pragma unroll
    for (int off = 16; off; off >>= 1) v += __shfl_xor(v, off);
    if (active && (tid & 31) == 0) distk[t*7 + u] = v;
  }
  __syncthreads();

  if constexpr (NZ == 2) {
    if (tid < NSH)
      partial[((size_t)(b*NBLK + blk)*NZ + z)*NSH + tid] = distk[tid];   // raw (unscaled)
  } else {
    if (tid < 64) {
      float v = (tid < NSH) ? distk[tid] : __builtin_inff();
#pragma unroll
      for (int off = 32; off; off >>= 1) v = fminf(v, __shfl_xor(v, off));
      if (tid == 0) partial[(size_t)b*NBLK + blk] = v;                   // raw min
    }
  }
}

template<int NZ>
__global__ void topk_kernel(const float* __restrict__ partial, float* __restrict__ out)
{
  const int b = blockIdx.x;            // 0..7
  const int lane = threadIdx.x;        // 0..63
  const float INF = __builtin_inff();

  float v0 = INF, v1 = INF, v2 = INF;
  if constexpr (NZ == 2) {
#pragma unroll
    for (int i = 0; i < 3; i++) {
      int blk = lane + 64*i;
      if (blk < NBLK) {
        const float* p = partial + (size_t)(b*NBLK + blk)*2*NSH;
        float m = INF;
        for (int k = 0; k < NSH; k++) m = fminf(m, p[k] + p[k+NSH]);
        if (i == 0) v0 = m; else if (i == 1) v1 = m; else v2 = m;
      }
    }
  } else {
    const float* p = partial + (size_t)b*NBLK;
    v0 = p[lane];
    v1 = p[lane + 64];
    v2 = (lane < 16) ? p[lane + 128] : INF;
  }

  float sum = 0.f;
  for (int it = 0; it < 16; ++it) {
    float lm = fminf(v0, fminf(v1, v2));
    float m = lm;
#pragma unroll
    for (int off = 32; off; off >>= 1) m = fminf(m, __shfl_xor(m, off));
    sum += m;
    unsigned long long mask = __ballot(lm == m);
    int leader = __ffsll(mask) - 1;
    if (lane == leader) {
      if (v0 == m)      v0 = INF;
      else if (v1 == m) v1 = INF;
      else              v2 = INF;
    }
  }
  if (lane == 0) out[b] = sum * (1.0f/((float)CC*SS*SS));
}

extern "C" void kernel_launch(void* const* d_in, const int* in_sizes, int n_in,
                              void* d_out, int out_size, void* d_ws, size_t ws_size,
                              hipStream_t stream)
{
  const float* fm1 = (const float*)d_in[0];
  const float* fm2 = (const float*)d_in[1];
  float* out  = (float*)d_out;
  float* scratch = (float*)d_ws;

  const size_t NEED = (size_t)8 * NBLK * 2 * NSH * sizeof(float);  // 451,584 B
  if (ws_size >= NEED) {
    dist_kernel<2><<<2*8*NBLK, 256, 0, stream>>>(fm1, fm2, scratch);
    topk_kernel<2><<<8, 64, 0, stream>>>(scratch, out);
  } else {
    dist_kernel<1><<<8*NBLK, 256, 0, stream>>>(fm1, fm2, scratch);
    topk_kernel<1><<<8, 64, 0, stream>>>(scratch, out);
  }
}